// Round 1
// baseline (538.595 us; speedup 1.0000x reference)
//
#include <hip/hip_runtime.h>
#include <hip/hip_bf16.h>
#include <stdint.h>

#define T_TOK 1024
#define HID   1024
#define INT_  4096
#define NE    8

typedef __attribute__((ext_vector_type(4))) float f32x4;
typedef __attribute__((ext_vector_type(8))) short short8;

__device__ __forceinline__ uint32_t pack2bf(float a, float b) {
  unsigned short ua = __builtin_bit_cast(unsigned short, (__bf16)a);
  unsigned short ub = __builtin_bit_cast(unsigned short, (__bf16)b);
  return (uint32_t)ua | ((uint32_t)ub << 16);
}

// ---------------- Kernel 1: act[e,t,i] = mask[t,e] * up * silu(gate) --------
// grid (INT_/128, T_TOK/128, NE), 256 threads.
__global__ __launch_bounds__(256, 2)
void k1_gateup(const float* __restrict__ x,        // [T_TOK][HID]
               const int*   __restrict__ mask,     // [T_TOK][NE]
               const float* __restrict__ wgu,      // [NE][HID][2*INT_]
               unsigned short* __restrict__ act)   // [NE][T_TOK][INT_] bf16 bits
{
  __shared__ char sA [128 * 64 * 2];   // [m][k] bf16, swizzled
  __shared__ char sBg[128 * 64 * 2];   // [n][k] bf16, swizzled
  __shared__ char sBu[128 * 64 * 2];

  const int nt = blockIdx.x;           // inter tile 0..31
  const int mt = blockIdx.y;           // token tile 0..7
  const int e  = blockIdx.z;

  const int tid  = threadIdx.x;
  const int lane = tid & 63;
  const int wv   = tid >> 6;
  const int wr   = (wv >> 1) * 64;     // wave row offset in tile
  const int wc   = (wv & 1)  * 64;     // wave col offset in tile

  const float* wb = wgu + (size_t)e * HID * (2 * INT_);
  const int t0 = mt * 128;
  const int n0 = nt * 128;

  f32x4 accg[4][4], accu[4][4];
  #pragma unroll
  for (int i = 0; i < 4; ++i)
    #pragma unroll
    for (int j = 0; j < 4; ++j) {
      accg[i][j] = (f32x4){0.f, 0.f, 0.f, 0.f};
      accu[i][j] = (f32x4){0.f, 0.f, 0.f, 0.f};
    }

  const int a_m = tid >> 4;            // 0..15
  const int a_k = (tid & 15) * 4;      // f32 elems, 0..60
  const int b_n = (tid >> 3) * 4;      // 0..124
  const int b_k = (tid & 7) * 4;       // 0..28

  for (int kt = 0; kt < HID; kt += 64) {
    // ---- stage A: x tile [128][64] f32 -> bf16 LDS [m][k]
    #pragma unroll
    for (int p = 0; p < 8; ++p) {
      const int m = p * 16 + a_m;
      f32x4 v = *(const f32x4*)(x + (size_t)(t0 + m) * HID + kt + a_k);
      uint2 w; w.x = pack2bf(v[0], v[1]); w.y = pack2bf(v[2], v[3]);
      *(uint2*)(sA + m * 128 + ((a_k * 2) ^ ((m & 7) << 4))) = w;
    }
    // ---- stage Bg/Bu: w rows [64][128] f32 -> transposed bf16 LDS [n][k]
    #pragma unroll
    for (int p = 0; p < 2; ++p) {
      const int kk = p * 32 + b_k;
      const float* src = wb + (size_t)(kt + kk) * (2 * INT_) + n0 + b_n;
      f32x4 g0 = *(const f32x4*)(src);
      f32x4 g1 = *(const f32x4*)(src + (2 * INT_));
      f32x4 g2 = *(const f32x4*)(src + 2 * (2 * INT_));
      f32x4 g3 = *(const f32x4*)(src + 3 * (2 * INT_));
      f32x4 u0 = *(const f32x4*)(src + INT_);
      f32x4 u1 = *(const f32x4*)(src + INT_ + (2 * INT_));
      f32x4 u2 = *(const f32x4*)(src + INT_ + 2 * (2 * INT_));
      f32x4 u3 = *(const f32x4*)(src + INT_ + 3 * (2 * INT_));
      #pragma unroll
      for (int n = 0; n < 4; ++n) {
        const int row = b_n + n;
        const int off = row * 128 + ((kk * 2) ^ ((row & 7) << 4));
        uint2 wg; wg.x = pack2bf(g0[n], g1[n]); wg.y = pack2bf(g2[n], g3[n]);
        *(uint2*)(sBg + off) = wg;
        uint2 wu; wu.x = pack2bf(u0[n], u1[n]); wu.y = pack2bf(u2[n], u3[n]);
        *(uint2*)(sBu + off) = wu;
      }
    }
    __syncthreads();
    // ---- compute: 2 k-sub-steps of K=32
    #pragma unroll
    for (int ks = 0; ks < 2; ++ks) {
      const int kfb = ks * 64 + ((lane >> 4) << 4);   // byte offset of lane's k-chunk
      short8 af[4], bg[4], bu[4];
      #pragma unroll
      for (int i = 0; i < 4; ++i) {
        const int r = wr + i * 16 + (lane & 15);
        af[i] = *(const short8*)(sA + r * 128 + (kfb ^ ((r & 7) << 4)));
      }
      #pragma unroll
      for (int i = 0; i < 4; ++i) {
        const int r = wc + i * 16 + (lane & 15);
        const int off = r * 128 + (kfb ^ ((r & 7) << 4));
        bg[i] = *(const short8*)(sBg + off);
        bu[i] = *(const short8*)(sBu + off);
      }
      #pragma unroll
      for (int i = 0; i < 4; ++i)
        #pragma unroll
        for (int j = 0; j < 4; ++j) {
          accg[i][j] = __builtin_amdgcn_mfma_f32_16x16x32_bf16(af[i], bg[j], accg[i][j], 0, 0, 0);
          accu[i][j] = __builtin_amdgcn_mfma_f32_16x16x32_bf16(af[i], bu[j], accu[i][j], 0, 0, 0);
        }
    }
    __syncthreads();
  }

  // ---- epilogue: act = mask * up * silu(gate), bf16 store
  unsigned short* ab = act + (size_t)e * T_TOK * INT_;
  #pragma unroll
  for (int i = 0; i < 4; ++i) {
    #pragma unroll
    for (int r = 0; r < 4; ++r) {
      const int trow = t0 + wr + i * 16 + ((lane >> 4) << 2) + r;
      const float mv = (float)mask[trow * NE + e];
      #pragma unroll
      for (int j = 0; j < 4; ++j) {
        const int col = n0 + wc + j * 16 + (lane & 15);
        const float g = accg[i][j][r];
        const float u = accu[i][j][r];
        const float s = mv * u * g / (1.f + __expf(-g));
        ab[(size_t)trow * INT_ + col] = __builtin_bit_cast(unsigned short, (__bf16)s);
      }
    }
  }
}

// ---------------- Kernel 2: out[t,h] += act[e] @ w_down[e] ------------------
// grid (HID/128, T_TOK/128, NE), 256 threads.
__global__ __launch_bounds__(256, 2)
void k2_down(const unsigned short* __restrict__ act,  // [NE][T_TOK][INT_] bf16
             const float* __restrict__ wd,            // [NE][INT_][HID]
             float* __restrict__ out)                 // [T_TOK][HID]
{
  __shared__ char sA[128 * 64 * 2];    // [m][k] bf16
  __shared__ char sB[128 * 64 * 2];    // [n][k] bf16

  const int nt = blockIdx.x;           // 0..7
  const int mt = blockIdx.y;           // 0..7
  const int e  = blockIdx.z;

  const int tid  = threadIdx.x;
  const int lane = tid & 63;
  const int wv   = tid >> 6;
  const int wr   = (wv >> 1) * 64;
  const int wc   = (wv & 1)  * 64;

  const unsigned short* ab = act + (size_t)e * T_TOK * INT_;
  const float* wb = wd + (size_t)e * INT_ * HID;
  const int t0 = mt * 128;
  const int n0 = nt * 128;

  f32x4 acc[4][4];
  #pragma unroll
  for (int i = 0; i < 4; ++i)
    #pragma unroll
    for (int j = 0; j < 4; ++j) acc[i][j] = (f32x4){0.f, 0.f, 0.f, 0.f};

  const int a_m = tid >> 3;            // 0..31
  const int a_k = (tid & 7) * 8;       // bf16 elems 0..56
  const int b_n = (tid >> 3) * 4;
  const int b_k = (tid & 7) * 4;

  for (int kt = 0; kt < INT_; kt += 64) {
    // ---- stage A: act tile (already bf16), direct 16B copies
    #pragma unroll
    for (int p = 0; p < 4; ++p) {
      const int m = p * 32 + a_m;
      uint4 v = *(const uint4*)(ab + (size_t)(t0 + m) * INT_ + kt + a_k);
      *(uint4*)(sA + m * 128 + ((a_k * 2) ^ ((m & 7) << 4))) = v;
    }
    // ---- stage B: w_down rows -> transposed bf16 LDS [n][k]
    #pragma unroll
    for (int p = 0; p < 2; ++p) {
      const int kk = p * 32 + b_k;
      const float* src = wb + (size_t)(kt + kk) * HID + n0 + b_n;
      f32x4 r0 = *(const f32x4*)(src);
      f32x4 r1 = *(const f32x4*)(src + HID);
      f32x4 r2 = *(const f32x4*)(src + 2 * HID);
      f32x4 r3 = *(const f32x4*)(src + 3 * HID);
      #pragma unroll
      for (int n = 0; n < 4; ++n) {
        const int row = b_n + n;
        uint2 w; w.x = pack2bf(r0[n], r1[n]); w.y = pack2bf(r2[n], r3[n]);
        *(uint2*)(sB + row * 128 + ((kk * 2) ^ ((row & 7) << 4))) = w;
      }
    }
    __syncthreads();
    #pragma unroll
    for (int ks = 0; ks < 2; ++ks) {
      const int kfb = ks * 64 + ((lane >> 4) << 4);
      short8 af[4], bf[4];
      #pragma unroll
      for (int i = 0; i < 4; ++i) {
        const int r = wr + i * 16 + (lane & 15);
        af[i] = *(const short8*)(sA + r * 128 + (kfb ^ ((r & 7) << 4)));
      }
      #pragma unroll
      for (int i = 0; i < 4; ++i) {
        const int r = wc + i * 16 + (lane & 15);
        bf[i] = *(const short8*)(sB + r * 128 + (kfb ^ ((r & 7) << 4)));
      }
      #pragma unroll
      for (int i = 0; i < 4; ++i)
        #pragma unroll
        for (int j = 0; j < 4; ++j)
          acc[i][j] = __builtin_amdgcn_mfma_f32_16x16x32_bf16(af[i], bf[j], acc[i][j], 0, 0, 0);
    }
    __syncthreads();
  }

  // ---- epilogue: accumulate into out (sum over experts via atomics)
  #pragma unroll
  for (int i = 0; i < 4; ++i) {
    #pragma unroll
    for (int r = 0; r < 4; ++r) {
      const int trow = t0 + wr + i * 16 + ((lane >> 4) << 2) + r;
      #pragma unroll
      for (int j = 0; j < 4; ++j) {
        const int col = n0 + wc + j * 16 + (lane & 15);
        atomicAdd(out + (size_t)trow * HID + col, acc[i][j][r]);
      }
    }
  }
}

extern "C" void kernel_launch(void* const* d_in, const int* in_sizes, int n_in,
                              void* d_out, int out_size, void* d_ws, size_t ws_size,
                              hipStream_t stream) {
  const float* x   = (const float*)d_in[0];
  const int*   idx = (const int*)d_in[1];
  const float* wgu = (const float*)d_in[2];
  const float* wd  = (const float*)d_in[3];
  float* out = (float*)d_out;
  unsigned short* act = (unsigned short*)d_ws;   // 8*1024*4096*2 = 64 MB

  hipMemsetAsync(d_out, 0, (size_t)out_size * sizeof(float), stream);

  dim3 g1(INT_ / 128, T_TOK / 128, NE);   // (32, 8, 8)
  k1_gateup<<<g1, dim3(256), 0, stream>>>(x, idx, wgu, act);

  dim3 g2(HID / 128, T_TOK / 128, NE);    // (8, 8, 8)
  k2_down<<<g2, dim3(256), 0, stream>>>(act, wd, out);
}

// Round 2
// 438.551 us; speedup vs baseline: 1.2281x; 1.2281x over previous
//
#include <hip/hip_runtime.h>
#include <hip/hip_bf16.h>
#include <stdint.h>

#define T_TOK 1024
#define HID   1024
#define INT_  4096
#define NE    8

typedef __attribute__((ext_vector_type(4))) float f32x4;
typedef __attribute__((ext_vector_type(8))) short short8;

__device__ int g_tok[NE][T_TOK];   // compacted token list per expert (slots >= cnt stay 0)
__device__ int g_cnt[NE];

__device__ __forceinline__ uint32_t pack2bf(float a, float b) {
  unsigned short ua = __builtin_bit_cast(unsigned short, (__bf16)a);
  unsigned short ub = __builtin_bit_cast(unsigned short, (__bf16)b);
  return (uint32_t)ua | ((uint32_t)ub << 16);
}

// ---------------- Kernel 0: per-expert token compaction ---------------------
// 1 block, 512 threads: wave e compacts expert e via ballot/popc scan.
__global__ void k0_compact(const int* __restrict__ mask)  // [T_TOK][NE]
{
  const int w    = threadIdx.x >> 6;
  const int lane = threadIdx.x & 63;
  if (w >= NE) return;
  const unsigned long long ltmask = (1ull << lane) - 1ull;
  int base = 0;
  #pragma unroll
  for (int c = 0; c < T_TOK / 64; ++c) {
    const int t = c * 64 + lane;
    const bool pred = mask[t * NE + w] != 0;
    const unsigned long long bal = __ballot(pred);
    if (pred) g_tok[w][base + __popcll(bal & ltmask)] = t;
    base += __popcll(bal);
  }
  if (lane == 0) g_cnt[w] = base;
}

// ---------------- Kernel 1: act[e,slot,i] = up * silu(gate) (compacted) -----
// grid (INT_/128, T_TOK/128, NE), 256 threads. Dead token-tiles exit early.
__global__ __launch_bounds__(256, 2)
void k1_gateup(const float* __restrict__ x,        // [T_TOK][HID]
               const float* __restrict__ wgu,      // [NE][HID][2*INT_]
               unsigned short* __restrict__ act)   // [NE][T_TOK][INT_] bf16 bits (compacted rows)
{
  const int e   = blockIdx.z;
  const int cnt = g_cnt[e];
  const int mt  = blockIdx.y;
  const int t0  = mt * 128;
  if (t0 >= cnt) return;

  __shared__ char sA [128 * 64 * 2];   // [m][k] bf16, swizzled
  __shared__ char sBg[128 * 64 * 2];   // [n][k] bf16, swizzled
  __shared__ char sBu[128 * 64 * 2];

  const int nt = blockIdx.x;
  const int tid  = threadIdx.x;
  const int lane = tid & 63;
  const int wv   = tid >> 6;
  const int wr   = (wv >> 1) * 64;
  const int wc   = (wv & 1)  * 64;

  const float* wb = wgu + (size_t)e * HID * (2 * INT_);
  const int n0 = nt * 128;

  f32x4 accg[4][4], accu[4][4];
  #pragma unroll
  for (int i = 0; i < 4; ++i)
    #pragma unroll
    for (int j = 0; j < 4; ++j) {
      accg[i][j] = (f32x4){0.f, 0.f, 0.f, 0.f};
      accu[i][j] = (f32x4){0.f, 0.f, 0.f, 0.f};
    }

  const int a_m = tid >> 4;            // 0..15
  const int a_k = (tid & 15) * 4;      // f32 elems, 0..60
  const int b_n = (tid >> 3) * 4;      // 0..124
  const int b_k = (tid & 7) * 4;       // 0..28

  // hoist this thread's 8 gathered token row indices (slots >= cnt read tok 0 -> garbage, discarded)
  int tokr[8];
  #pragma unroll
  for (int p = 0; p < 8; ++p) tokr[p] = g_tok[e][t0 + p * 16 + a_m];

  for (int kt = 0; kt < HID; kt += 64) {
    // ---- stage A: gathered x rows [128][64] f32 -> bf16 LDS [m][k]
    #pragma unroll
    for (int p = 0; p < 8; ++p) {
      const int m = p * 16 + a_m;
      f32x4 v = *(const f32x4*)(x + (size_t)tokr[p] * HID + kt + a_k);
      uint2 w; w.x = pack2bf(v[0], v[1]); w.y = pack2bf(v[2], v[3]);
      *(uint2*)(sA + m * 128 + ((a_k * 2) ^ ((m & 7) << 4))) = w;
    }
    // ---- stage Bg/Bu: w rows [64][128] f32 -> transposed bf16 LDS [n][k]
    #pragma unroll
    for (int p = 0; p < 2; ++p) {
      const int kk = p * 32 + b_k;
      const float* src = wb + (size_t)(kt + kk) * (2 * INT_) + n0 + b_n;
      f32x4 g0 = *(const f32x4*)(src);
      f32x4 g1 = *(const f32x4*)(src + (2 * INT_));
      f32x4 g2 = *(const f32x4*)(src + 2 * (2 * INT_));
      f32x4 g3 = *(const f32x4*)(src + 3 * (2 * INT_));
      f32x4 u0 = *(const f32x4*)(src + INT_);
      f32x4 u1 = *(const f32x4*)(src + INT_ + (2 * INT_));
      f32x4 u2 = *(const f32x4*)(src + INT_ + 2 * (2 * INT_));
      f32x4 u3 = *(const f32x4*)(src + INT_ + 3 * (2 * INT_));
      #pragma unroll
      for (int n = 0; n < 4; ++n) {
        const int row = b_n + n;
        const int off = row * 128 + ((kk * 2) ^ ((row & 7) << 4));
        uint2 wg; wg.x = pack2bf(g0[n], g1[n]); wg.y = pack2bf(g2[n], g3[n]);
        *(uint2*)(sBg + off) = wg;
        uint2 wu; wu.x = pack2bf(u0[n], u1[n]); wu.y = pack2bf(u2[n], u3[n]);
        *(uint2*)(sBu + off) = wu;
      }
    }
    __syncthreads();
    #pragma unroll
    for (int ks = 0; ks < 2; ++ks) {
      const int kfb = ks * 64 + ((lane >> 4) << 4);
      short8 af[4], bg[4], bu[4];
      #pragma unroll
      for (int i = 0; i < 4; ++i) {
        const int r = wr + i * 16 + (lane & 15);
        af[i] = *(const short8*)(sA + r * 128 + (kfb ^ ((r & 7) << 4)));
      }
      #pragma unroll
      for (int i = 0; i < 4; ++i) {
        const int r = wc + i * 16 + (lane & 15);
        const int off = r * 128 + (kfb ^ ((r & 7) << 4));
        bg[i] = *(const short8*)(sBg + off);
        bu[i] = *(const short8*)(sBu + off);
      }
      #pragma unroll
      for (int i = 0; i < 4; ++i)
        #pragma unroll
        for (int j = 0; j < 4; ++j) {
          accg[i][j] = __builtin_amdgcn_mfma_f32_16x16x32_bf16(af[i], bg[j], accg[i][j], 0, 0, 0);
          accu[i][j] = __builtin_amdgcn_mfma_f32_16x16x32_bf16(af[i], bu[j], accu[i][j], 0, 0, 0);
        }
    }
    __syncthreads();
  }

  // ---- epilogue: act = up * silu(gate) (mask==1 for all compacted rows)
  unsigned short* ab = act + (size_t)e * T_TOK * INT_;
  #pragma unroll
  for (int i = 0; i < 4; ++i) {
    #pragma unroll
    for (int r = 0; r < 4; ++r) {
      const int slot = t0 + wr + i * 16 + ((lane >> 4) << 2) + r;
      if (slot < cnt) {
        #pragma unroll
        for (int j = 0; j < 4; ++j) {
          const int col = n0 + wc + j * 16 + (lane & 15);
          const float g = accg[i][j][r];
          const float u = accu[i][j][r];
          const float s = u * g / (1.f + __expf(-g));
          ab[(size_t)slot * INT_ + col] = __builtin_bit_cast(unsigned short, (__bf16)s);
        }
      }
    }
  }
}

// ---------------- Kernel 2: out[tok[slot],h] += act[e,slot] @ w_down[e] -----
// grid (HID/128, T_TOK/128, NE), 256 threads. Dead token-tiles exit early.
__global__ __launch_bounds__(256, 2)
void k2_down(const unsigned short* __restrict__ act,  // [NE][T_TOK][INT_] bf16 (compacted)
             const float* __restrict__ wd,            // [NE][INT_][HID]
             float* __restrict__ out)                 // [T_TOK][HID]
{
  const int e   = blockIdx.z;
  const int cnt = g_cnt[e];
  const int mt  = blockIdx.y;
  const int t0  = mt * 128;
  if (t0 >= cnt) return;

  __shared__ char sA[128 * 64 * 2];
  __shared__ char sB[128 * 64 * 2];

  const int nt = blockIdx.x;
  const int tid  = threadIdx.x;
  const int lane = tid & 63;
  const int wv   = tid >> 6;
  const int wr   = (wv >> 1) * 64;
  const int wc   = (wv & 1)  * 64;

  const unsigned short* ab = act + (size_t)e * T_TOK * INT_;
  const float* wb = wd + (size_t)e * INT_ * HID;
  const int n0 = nt * 128;

  f32x4 acc[4][4];
  #pragma unroll
  for (int i = 0; i < 4; ++i)
    #pragma unroll
    for (int j = 0; j < 4; ++j) acc[i][j] = (f32x4){0.f, 0.f, 0.f, 0.f};

  const int a_m = tid >> 3;            // 0..31
  const int a_k = (tid & 7) * 8;       // bf16 elems 0..56
  const int b_n = (tid >> 3) * 4;
  const int b_k = (tid & 7) * 4;

  for (int kt = 0; kt < INT_; kt += 64) {
    #pragma unroll
    for (int p = 0; p < 4; ++p) {
      const int m = p * 32 + a_m;
      uint4 v = *(const uint4*)(ab + (size_t)(t0 + m) * INT_ + kt + a_k);
      *(uint4*)(sA + m * 128 + ((a_k * 2) ^ ((m & 7) << 4))) = v;
    }
    #pragma unroll
    for (int p = 0; p < 2; ++p) {
      const int kk = p * 32 + b_k;
      const float* src = wb + (size_t)(kt + kk) * HID + n0 + b_n;
      f32x4 r0 = *(const f32x4*)(src);
      f32x4 r1 = *(const f32x4*)(src + HID);
      f32x4 r2 = *(const f32x4*)(src + 2 * HID);
      f32x4 r3 = *(const f32x4*)(src + 3 * HID);
      #pragma unroll
      for (int n = 0; n < 4; ++n) {
        const int row = b_n + n;
        uint2 w; w.x = pack2bf(r0[n], r1[n]); w.y = pack2bf(r2[n], r3[n]);
        *(uint2*)(sB + row * 128 + ((kk * 2) ^ ((row & 7) << 4))) = w;
      }
    }
    __syncthreads();
    #pragma unroll
    for (int ks = 0; ks < 2; ++ks) {
      const int kfb = ks * 64 + ((lane >> 4) << 4);
      short8 af[4], bf[4];
      #pragma unroll
      for (int i = 0; i < 4; ++i) {
        const int r = wr + i * 16 + (lane & 15);
        af[i] = *(const short8*)(sA + r * 128 + (kfb ^ ((r & 7) << 4)));
      }
      #pragma unroll
      for (int i = 0; i < 4; ++i) {
        const int r = wc + i * 16 + (lane & 15);
        bf[i] = *(const short8*)(sB + r * 128 + (kfb ^ ((r & 7) << 4)));
      }
      #pragma unroll
      for (int i = 0; i < 4; ++i)
        #pragma unroll
        for (int j = 0; j < 4; ++j)
          acc[i][j] = __builtin_amdgcn_mfma_f32_16x16x32_bf16(af[i], bf[j], acc[i][j], 0, 0, 0);
    }
    __syncthreads();
  }

  // ---- epilogue: scatter-accumulate valid rows into out
  #pragma unroll
  for (int i = 0; i < 4; ++i) {
    #pragma unroll
    for (int r = 0; r < 4; ++r) {
      const int slot = t0 + wr + i * 16 + ((lane >> 4) << 2) + r;
      if (slot < cnt) {
        const int token = g_tok[e][slot];
        #pragma unroll
        for (int j = 0; j < 4; ++j) {
          const int col = n0 + wc + j * 16 + (lane & 15);
          atomicAdd(out + (size_t)token * HID + col, acc[i][j][r]);
        }
      }
    }
  }
}

extern "C" void kernel_launch(void* const* d_in, const int* in_sizes, int n_in,
                              void* d_out, int out_size, void* d_ws, size_t ws_size,
                              hipStream_t stream) {
  const float* x   = (const float*)d_in[0];
  const int*   idx = (const int*)d_in[1];
  const float* wgu = (const float*)d_in[2];
  const float* wd  = (const float*)d_in[3];
  float* out = (float*)d_out;
  unsigned short* act = (unsigned short*)d_ws;   // 64 MB

  hipMemsetAsync(d_out, 0, (size_t)out_size * sizeof(float), stream);

  k0_compact<<<1, 512, 0, stream>>>(idx);

  dim3 g1(INT_ / 128, T_TOK / 128, NE);   // (32, 8, 8)
  k1_gateup<<<g1, dim3(256), 0, stream>>>(x, wgu, act);

  dim3 g2(HID / 128, T_TOK / 128, NE);    // (8, 8, 8)
  k2_down<<<g2, dim3(256), 0, stream>>>(act, wd, out);
}